// Round 2
// baseline (3692.520 us; speedup 1.0000x reference)
//
#include <hip/hip_runtime.h>

// HNHN layer on MI355X.
// Pipeline:
//  K0 fuse_weights: Wf = W1@Wve, bf = b1@Wve + bve           (tiny)
//  K1 gemm128:      Whv' = (vfeat@Wf + bf) * v_reg_weight     [N_V,128] -> ws
//  K2 agg:          feat_e[e] += (1/e_reg_sum[e]) * Whv'[n]   (atomics into d_out chunk2)
//  K3 gemm128:      Whe' = (feat_e@Wev + bev) * e_reg_weight  [N_E,128] -> ws (reuse)
//  K4 agg:          feat_v_out[v] += (1/v_reg_sum[v]) * Whe'[e] (atomics into d_out chunk1)

#define BM 128
#define BK 32

__global__ void fuse_weights(const float* __restrict__ W1, const float* __restrict__ b1,
                             const float* __restrict__ Wve, const float* __restrict__ bve,
                             float* __restrict__ Wf, float* __restrict__ bf) {
    int i = blockIdx.x;          // 0..127 rows of W1; 128 => bias row
    int j = threadIdx.x;         // 0..127
    float acc = 0.f;
    if (i < 128) {
        #pragma unroll 8
        for (int k = 0; k < 128; ++k)
            acc = fmaf(W1[i * 128 + k], Wve[k * 128 + j], acc);
        Wf[i * 128 + j] = acc;
    } else {
        #pragma unroll 8
        for (int k = 0; k < 128; ++k)
            acc = fmaf(b1[k], Wve[k * 128 + j], acc);
        bf[j] = acc + bve[j];
    }
}

// C = (A[M,128] @ B[128,128] + bias) * rowscale[row], row-major.
// 256 threads, BM=128 rows/block, full N=128, K chunked by 32.
// Thread tile 8x8: ty=t>>4 -> rows, tx=t&15 -> cols.
__global__ __launch_bounds__(256)
void gemm128(const float* __restrict__ A, const float* __restrict__ B,
             const float* __restrict__ bias, const float* __restrict__ rowscale,
             float* __restrict__ out, int M) {
    __shared__ float As[BK][BM];    // transposed: As[k][m]
    __shared__ float Bs[BK][128];

    const int t = threadIdx.x;
    const int row0 = blockIdx.x * BM;
    const int tx = t & 15;
    const int ty = t >> 4;
    const int m0 = ty * 8;
    const int n0 = tx * 8;

    float acc[8][8];
    #pragma unroll
    for (int i = 0; i < 8; ++i)
        #pragma unroll
        for (int j = 0; j < 8; ++j) acc[i][j] = 0.f;

    for (int k0 = 0; k0 < 128; k0 += BK) {
        // stage A tile (128 rows x 32 cols) transposed into As[k][m]
        #pragma unroll
        for (int p = 0; p < 4; ++p) {
            int f = t + p * 256;          // 0..1023 float4 id
            int r = f >> 3;               // row in tile 0..127
            int cv = f & 7;               // float4 col 0..7
            int gr = row0 + r;
            float4 v = make_float4(0.f, 0.f, 0.f, 0.f);
            if (gr < M) v = *(const float4*)(&A[(size_t)gr * 128 + k0 + cv * 4]);
            As[cv * 4 + 0][r] = v.x;
            As[cv * 4 + 1][r] = v.y;
            As[cv * 4 + 2][r] = v.z;
            As[cv * 4 + 3][r] = v.w;
        }
        // stage B tile (32 rows x 128 cols)
        #pragma unroll
        for (int p = 0; p < 4; ++p) {
            int f = t + p * 256;
            int r = f >> 5;               // 0..31
            int cv = f & 31;              // float4 col 0..31
            *(float4*)(&Bs[r][cv * 4]) = *(const float4*)(&B[(size_t)(k0 + r) * 128 + cv * 4]);
        }
        __syncthreads();

        #pragma unroll
        for (int k = 0; k < BK; ++k) {
            float a[8], b[8];
            *(float4*)&a[0] = *(const float4*)&As[k][m0];
            *(float4*)&a[4] = *(const float4*)&As[k][m0 + 4];
            *(float4*)&b[0] = *(const float4*)&Bs[k][n0];
            *(float4*)&b[4] = *(const float4*)&Bs[k][n0 + 4];
            #pragma unroll
            for (int i = 0; i < 8; ++i)
                #pragma unroll
                for (int j = 0; j < 8; ++j)
                    acc[i][j] = fmaf(a[i], b[j], acc[i][j]);
        }
        __syncthreads();
    }

    // epilogue: add bias, scale by rowscale, store
    float bb[8];
    #pragma unroll
    for (int j = 0; j < 8; ++j) bb[j] = bias[n0 + j];

    #pragma unroll
    for (int i = 0; i < 8; ++i) {
        int gr = row0 + m0 + i;
        if (gr < M) {
            float rs = rowscale[gr];
            float o[8];
            #pragma unroll
            for (int j = 0; j < 8; ++j) o[j] = (acc[i][j] + bb[j]) * rs;
            *(float4*)(&out[(size_t)gr * 128 + n0]) = *(float4*)&o[0];
            *(float4*)(&out[(size_t)gr * 128 + n0 + 4]) = *(float4*)&o[4];
        }
    }
}

// Per nnz i: dst[sidx[i]][:] += (1/sum_tbl[sidx[i]]) * src[gidx[i]][:]
// 32 lanes per nnz, float4 per lane; 8 nnz per 256-thread block.
__global__ __launch_bounds__(256)
void agg(const float* __restrict__ src, const int* __restrict__ gidx,
         const int* __restrict__ sidx, const float* __restrict__ sum_tbl,
         float* __restrict__ dst, int nnz) {
    const int lane = threadIdx.x & 31;
    int grp = (blockIdx.x * 256 + threadIdx.x) >> 5;
    const int ngrp = (gridDim.x * 256) >> 5;
    for (int i = grp; i < nnz; i += ngrp) {
        int g = gidx[i];
        int s = sidx[i];
        float sc = 1.0f / sum_tbl[s];
        float4 v = *(const float4*)(&src[(size_t)g * 128 + lane * 4]);
        float* d = &dst[(size_t)s * 128 + lane * 4];
        unsafeAtomicAdd(d + 0, v.x * sc);
        unsafeAtomicAdd(d + 1, v.y * sc);
        unsafeAtomicAdd(d + 2, v.z * sc);
        unsafeAtomicAdd(d + 3, v.w * sc);
    }
}

extern "C" void kernel_launch(void* const* d_in, const int* in_sizes, int n_in,
                              void* d_out, int out_size, void* d_ws, size_t ws_size,
                              hipStream_t stream) {
    const float* vfeat        = (const float*)d_in[0];
    // d_in[1] efeat: unused by the reference math
    const float* v_reg_weight = (const float*)d_in[2];
    const float* v_reg_sum    = (const float*)d_in[3];
    const float* e_reg_weight = (const float*)d_in[4];
    const float* e_reg_sum    = (const float*)d_in[5];
    const int*   node_idx     = (const int*)d_in[6];
    const int*   edge_idx     = (const int*)d_in[7];
    const float* W1           = (const float*)d_in[8];
    const float* b1           = (const float*)d_in[9];
    const float* Wve          = (const float*)d_in[10];
    const float* bve          = (const float*)d_in[11];
    const float* Wev          = (const float*)d_in[12];
    const float* bev          = (const float*)d_in[13];

    const int N_V = in_sizes[0] / 128;   // 200000
    const int N_E = in_sizes[4];         // 40000 (e_reg_weight is [N_E,1])
    const int NNZ = in_sizes[6];         // 1000000

    float* ws  = (float*)d_ws;
    float* Wf  = ws;                     // 16384 floats
    float* bf  = ws + 16384;             // 128 floats
    float* Whv = ws + 16640;             // N_V*128 floats; reused for Whe after K2

    float* feat_v_out = (float*)d_out;                       // [N_V,128]
    float* feat_e     = (float*)d_out + (size_t)N_V * 128;   // [N_E,128]

    // outputs are accumulated with atomics -> zero them (harness poisons 0xAA)
    hipMemsetAsync(d_out, 0, (size_t)out_size * sizeof(float), stream);

    fuse_weights<<<129, 128, 0, stream>>>(W1, b1, Wve, bve, Wf, bf);

    gemm128<<<(N_V + BM - 1) / BM, 256, 0, stream>>>(vfeat, Wf, bf, v_reg_weight, Whv, N_V);

    agg<<<(NNZ + 7) / 8, 256, 0, stream>>>(Whv, node_idx, edge_idx, e_reg_sum, feat_e, NNZ);

    gemm128<<<(N_E + BM - 1) / BM, 256, 0, stream>>>(feat_e, Wev, bev, e_reg_weight, Whv, N_E);

    agg<<<(NNZ + 7) / 8, 256, 0, stream>>>(Whv, edge_idx, node_idx, v_reg_sum, feat_v_out, NNZ);
}

// Round 3
// 767.362 us; speedup vs baseline: 4.8120x; 4.8120x over previous
//
#include <hip/hip_runtime.h>

// HNHN layer on MI355X — atomic-free aggregation via device-side counting sort.
// Pipeline:
//  K0 fuse_weights: Wf = W1@Wve, bf = b1@Wve + bve                  (tiny)
//  K1 hist:         cnt_e[e]++, cnt_v[v]++ per nnz                  (int atomics)
//  K2 alloc_ranges: start_e/v via wave-scan + one atomic per wave   (order-free)
//  K3 gemm128:      Whv' = (vfeat@Wf + bf) * v_reg_weight  -> d_out chunk1 (scratch)
//  K4 scatter:      src_e[pos]=node_idx, src_v[pos]=edge_idx        (int atomics)
//  K5 gather:       feat_e[e] = (1/e_reg_sum[e]) * sum Whv'[src_e]  (no atomics)
//  K6 gemm128:      Whe' = (feat_e@Wev + bev) * e_reg_weight -> ws
//  K7 gather:       feat_v[v] = (1/v_reg_sum[v]) * sum Whe'[src_v]  (overwrites scratch)

#define BM 128
#define BK 32

static __device__ __forceinline__ float4 f4add(float4 a, float4 b) {
    return make_float4(a.x + b.x, a.y + b.y, a.z + b.z, a.w + b.w);
}

__global__ void fuse_weights(const float* __restrict__ W1, const float* __restrict__ b1,
                             const float* __restrict__ Wve, const float* __restrict__ bve,
                             float* __restrict__ Wf, float* __restrict__ bf) {
    int i = blockIdx.x;          // 0..127 rows of W1; 128 => bias row
    int j = threadIdx.x;         // 0..127
    float acc = 0.f;
    if (i < 128) {
        #pragma unroll 8
        for (int k = 0; k < 128; ++k)
            acc = fmaf(W1[i * 128 + k], Wve[k * 128 + j], acc);
        Wf[i * 128 + j] = acc;
    } else {
        #pragma unroll 8
        for (int k = 0; k < 128; ++k)
            acc = fmaf(b1[k], Wve[k * 128 + j], acc);
        bf[j] = acc + bve[j];
    }
}

// C = (A[M,128] @ B[128,128] + bias) * rowscale[row], row-major.
__global__ __launch_bounds__(256)
void gemm128(const float* __restrict__ A, const float* __restrict__ B,
             const float* __restrict__ bias, const float* __restrict__ rowscale,
             float* __restrict__ out, int M) {
    __shared__ float As[BK][BM];    // transposed: As[k][m]
    __shared__ float Bs[BK][128];

    const int t = threadIdx.x;
    const int row0 = blockIdx.x * BM;
    const int tx = t & 15;
    const int ty = t >> 4;
    const int m0 = ty * 8;
    const int n0 = tx * 8;

    float acc[8][8];
    #pragma unroll
    for (int i = 0; i < 8; ++i)
        #pragma unroll
        for (int j = 0; j < 8; ++j) acc[i][j] = 0.f;

    for (int k0 = 0; k0 < 128; k0 += BK) {
        #pragma unroll
        for (int p = 0; p < 4; ++p) {
            int f = t + p * 256;          // 0..1023 float4 id
            int r = f >> 3;               // row in tile 0..127
            int cv = f & 7;               // float4 col 0..7
            int gr = row0 + r;
            float4 v = make_float4(0.f, 0.f, 0.f, 0.f);
            if (gr < M) v = *(const float4*)(&A[(size_t)gr * 128 + k0 + cv * 4]);
            As[cv * 4 + 0][r] = v.x;
            As[cv * 4 + 1][r] = v.y;
            As[cv * 4 + 2][r] = v.z;
            As[cv * 4 + 3][r] = v.w;
        }
        #pragma unroll
        for (int p = 0; p < 4; ++p) {
            int f = t + p * 256;
            int r = f >> 5;               // 0..31
            int cv = f & 31;              // float4 col 0..31
            *(float4*)(&Bs[r][cv * 4]) = *(const float4*)(&B[(size_t)(k0 + r) * 128 + cv * 4]);
        }
        __syncthreads();

        #pragma unroll
        for (int k = 0; k < BK; ++k) {
            float a[8], b[8];
            *(float4*)&a[0] = *(const float4*)&As[k][m0];
            *(float4*)&a[4] = *(const float4*)&As[k][m0 + 4];
            *(float4*)&b[0] = *(const float4*)&Bs[k][n0];
            *(float4*)&b[4] = *(const float4*)&Bs[k][n0 + 4];
            #pragma unroll
            for (int i = 0; i < 8; ++i)
                #pragma unroll
                for (int j = 0; j < 8; ++j)
                    acc[i][j] = fmaf(a[i], b[j], acc[i][j]);
        }
        __syncthreads();
    }

    float bb[8];
    #pragma unroll
    for (int j = 0; j < 8; ++j) bb[j] = bias[n0 + j];

    #pragma unroll
    for (int i = 0; i < 8; ++i) {
        int gr = row0 + m0 + i;
        if (gr < M) {
            float rs = rowscale[gr];
            float o[8];
            #pragma unroll
            for (int j = 0; j < 8; ++j) o[j] = (acc[i][j] + bb[j]) * rs;
            *(float4*)(&out[(size_t)gr * 128 + n0]) = *(float4*)&o[0];
            *(float4*)(&out[(size_t)gr * 128 + n0 + 4]) = *(float4*)&o[4];
        }
    }
}

__global__ __launch_bounds__(256)
void hist(const int* __restrict__ node_idx, const int* __restrict__ edge_idx,
          int* __restrict__ cnt_e, int* __restrict__ cnt_v, int nnz) {
    int i = blockIdx.x * 256 + threadIdx.x;
    if (i < nnz) {
        atomicAdd(&cnt_e[edge_idx[i]], 1);
        atomicAdd(&cnt_v[node_idx[i]], 1);
    }
}

// Disjoint-range allocation: wave-level exclusive scan of counts, one global
// fetch-add per wave. Bucket ORDER in src arrays is arbitrary (only start+len
// matter), so no grid-wide prefix scan is needed.
// REQUIRES: ne % 64 == 0 and (ne+nv) % 64 == 0 so isE/oob are wave-uniform.
__global__ __launch_bounds__(256)
void alloc_ranges(const int* __restrict__ cnt_e, const int* __restrict__ cnt_v,
                  int* __restrict__ start_e, int* __restrict__ cursor_e,
                  int* __restrict__ start_v, int* __restrict__ cursor_v,
                  int* __restrict__ ctr, int ne, int nv) {
    int gid = blockIdx.x * 256 + threadIdx.x;
    int lane = threadIdx.x & 63;
    int total = ne + nv;
    if (gid - lane >= total) return;            // whole wave out of range
    bool isE = gid < ne;                        // wave-uniform (ne % 64 == 0)
    int idx = isE ? gid : gid - ne;
    int c = (gid < total) ? (isE ? cnt_e[idx] : cnt_v[idx]) : 0;
    int x = c;                                  // inclusive wave scan
    #pragma unroll
    for (int d = 1; d < 64; d <<= 1) {
        int y = __shfl_up(x, d);
        if (lane >= d) x += y;
    }
    int base;
    if (lane == 63) base = atomicAdd(isE ? &ctr[0] : &ctr[1], x);
    base = __shfl(base, 63);
    int pos = base + (x - c);
    if (gid < total) {
        if (isE) { start_e[idx] = pos; cursor_e[idx] = pos; }
        else     { start_v[idx] = pos; cursor_v[idx] = pos; }
    }
}

__global__ __launch_bounds__(256)
void scatter(const int* __restrict__ node_idx, const int* __restrict__ edge_idx,
             int* __restrict__ cursor_e, int* __restrict__ cursor_v,
             int* __restrict__ src_e, int* __restrict__ src_v, int nnz) {
    int i = blockIdx.x * 256 + threadIdx.x;
    if (i < nnz) {
        int n = node_idx[i], e = edge_idx[i];
        int pe = atomicAdd(&cursor_e[e], 1);
        src_e[pe] = n;
        int pv = atomicAdd(&cursor_v[n], 1);
        src_v[pv] = e;
    }
}

// dst[seg][:] = (1/inv_tbl[seg]) * sum_{j} src[srcidx[start[seg]+j]][:]
// 32 lanes per segment (float4/lane), 4 independent accumulators for MLP.
__global__ __launch_bounds__(256)
void gather_rows(const float* __restrict__ src, const int* __restrict__ srcidx,
                 const int* __restrict__ start, const int* __restrict__ cnt,
                 const float* __restrict__ sum_tbl, float* __restrict__ dst, int nseg) {
    const int lane = threadIdx.x & 31;
    int seg = (blockIdx.x * 256 + threadIdx.x) >> 5;
    if (seg >= nseg) return;
    const int st = start[seg];
    const int len = cnt[seg];
    const int c4 = lane * 4;
    float4 a0 = make_float4(0, 0, 0, 0), a1 = a0, a2 = a0, a3 = a0;
    int j = 0;
    for (; j + 4 <= len; j += 4) {
        int n0 = srcidx[st + j + 0];
        int n1 = srcidx[st + j + 1];
        int n2 = srcidx[st + j + 2];
        int n3 = srcidx[st + j + 3];
        a0 = f4add(a0, *(const float4*)(&src[(size_t)n0 * 128 + c4]));
        a1 = f4add(a1, *(const float4*)(&src[(size_t)n1 * 128 + c4]));
        a2 = f4add(a2, *(const float4*)(&src[(size_t)n2 * 128 + c4]));
        a3 = f4add(a3, *(const float4*)(&src[(size_t)n3 * 128 + c4]));
    }
    for (; j < len; ++j) {
        int n = srcidx[st + j];
        a0 = f4add(a0, *(const float4*)(&src[(size_t)n * 128 + c4]));
    }
    float sc = 1.0f / sum_tbl[seg];
    float4 r = f4add(f4add(a0, a1), f4add(a2, a3));
    r.x *= sc; r.y *= sc; r.z *= sc; r.w *= sc;
    *(float4*)(&dst[(size_t)seg * 128 + c4]) = r;
}

extern "C" void kernel_launch(void* const* d_in, const int* in_sizes, int n_in,
                              void* d_out, int out_size, void* d_ws, size_t ws_size,
                              hipStream_t stream) {
    const float* vfeat        = (const float*)d_in[0];
    const float* v_reg_weight = (const float*)d_in[2];
    const float* v_reg_sum    = (const float*)d_in[3];
    const float* e_reg_weight = (const float*)d_in[4];
    const float* e_reg_sum    = (const float*)d_in[5];
    const int*   node_idx     = (const int*)d_in[6];
    const int*   edge_idx     = (const int*)d_in[7];
    const float* W1           = (const float*)d_in[8];
    const float* b1           = (const float*)d_in[9];
    const float* Wve          = (const float*)d_in[10];
    const float* bve          = (const float*)d_in[11];
    const float* Wev          = (const float*)d_in[12];
    const float* bev          = (const float*)d_in[13];

    const int N_V = in_sizes[2];   // 200000
    const int N_E = in_sizes[4];   // 40000
    const int NNZ = in_sizes[6];   // 1000000

    // ---- ws layout (bytes) ----
    char* w = (char*)d_ws;
    float* Wf       = (float*)(w + 0);          //    65,536
    float* bf       = (float*)(w + 65536);      //       512
    float* Whe      = (float*)(w + 66048);      // 20,480,000  [N_E,128]
    int*   cnt_e    = (int*)(w + 20546048);     //   160,000
    int*   cnt_v    = (int*)(w + 20706048);     //   800,000
    int*   ctr      = (int*)(w + 21506048);     //         8
    // zero region: cnt_e..ctr = 960,008 B starting at 20546048
    int*   start_e  = (int*)(w + 21506056);     //   160,000
    int*   cursor_e = (int*)(w + 21666056);     //   160,000
    int*   start_v  = (int*)(w + 21826056);     //   800,000
    int*   cursor_v = (int*)(w + 22626056);     //   800,000
    int*   src_e    = (int*)(w + 23426056);     // 4,000,000
    int*   src_v    = (int*)(w + 27426056);     // 4,000,000  (end 31,426,056)

    float* feat_v_out = (float*)d_out;                       // [N_V,128]
    float* feat_e     = (float*)d_out + (size_t)N_V * 128;   // [N_E,128]
    float* Whv        = feat_v_out;  // chunk1 doubles as scratch for Whv' (dead
                                     // before the final gather overwrites it)

    hipMemsetAsync(w + 20546048, 0, 960008, stream);

    fuse_weights<<<129, 128, 0, stream>>>(W1, b1, Wve, bve, Wf, bf);

    hist<<<(NNZ + 255) / 256, 256, 0, stream>>>(node_idx, edge_idx, cnt_e, cnt_v, NNZ);

    alloc_ranges<<<(N_E + N_V + 255) / 256, 256, 0, stream>>>(
        cnt_e, cnt_v, start_e, cursor_e, start_v, cursor_v, ctr, N_E, N_V);

    gemm128<<<(N_V + BM - 1) / BM, 256, 0, stream>>>(vfeat, Wf, bf, v_reg_weight, Whv, N_V);

    scatter<<<(NNZ + 255) / 256, 256, 0, stream>>>(node_idx, edge_idx,
                                                   cursor_e, cursor_v, src_e, src_v, NNZ);

    gather_rows<<<(N_E * 32 + 255) / 256, 256, 0, stream>>>(
        Whv, src_e, start_e, cnt_e, e_reg_sum, feat_e, N_E);

    gemm128<<<(N_E + BM - 1) / BM, 256, 0, stream>>>(feat_e, Wev, bev, e_reg_weight, Whe, N_E);

    gather_rows<<<(N_V * 32 + 255) / 256, 256, 0, stream>>>(
        Whe, src_v, start_v, cnt_v, v_reg_sum, feat_v_out, N_V);
}

// Round 4
// 683.703 us; speedup vs baseline: 5.4008x; 1.1224x over previous
//
#include <hip/hip_runtime.h>

// HNHN layer on MI355X — atomic-free aggregation via device-side counting sort,
// with XCD-range-partitioned histogram/scatter (random writes stay in one L2).
// Pipeline:
//  K0 fuse_weights: Wf = W1@Wve, bf = b1@Wve + bve                  (tiny)
//  K1 hist16:       cnt_e[e]++, cnt_v[v]++  (16 groups, key-range filtered)
//  K2 alloc_ranges: start_e/v via wave-scan + one atomic per wave   (order-free)
//  K3 gemm128:      Whv' = (vfeat@Wf + bf) * v_reg_weight  -> d_out chunk1 (scratch)
//  K4 scatter16:    src_e[pos]=node_idx, src_v[pos]=edge_idx (16 groups)
//  K5 gather:       feat_e[e] = (1/e_reg_sum[e]) * sum Whv'[src_e]  (no atomics)
//  K6 gemm128:      Whe' = (feat_e@Wev + bev) * e_reg_weight -> ws
//  K7 gather:       feat_v[v] = (1/v_reg_sum[v]) * sum Whe'[src_v]  (overwrites scratch)

#define BM 128
#define BK 32

static __device__ __forceinline__ float4 f4add(float4 a, float4 b) {
    return make_float4(a.x + b.x, a.y + b.y, a.z + b.z, a.w + b.w);
}

__global__ void fuse_weights(const float* __restrict__ W1, const float* __restrict__ b1,
                             const float* __restrict__ Wve, const float* __restrict__ bve,
                             float* __restrict__ Wf, float* __restrict__ bf) {
    int i = blockIdx.x;          // 0..127 rows of W1; 128 => bias row
    int j = threadIdx.x;         // 0..127
    float acc = 0.f;
    if (i < 128) {
        #pragma unroll 8
        for (int k = 0; k < 128; ++k)
            acc = fmaf(W1[i * 128 + k], Wve[k * 128 + j], acc);
        Wf[i * 128 + j] = acc;
    } else {
        #pragma unroll 8
        for (int k = 0; k < 128; ++k)
            acc = fmaf(b1[k], Wve[k * 128 + j], acc);
        bf[j] = acc + bve[j];
    }
}

// C = (A[M,128] @ B[128,128] + bias) * rowscale[row], row-major.
__global__ __launch_bounds__(256)
void gemm128(const float* __restrict__ A, const float* __restrict__ B,
             const float* __restrict__ bias, const float* __restrict__ rowscale,
             float* __restrict__ out, int M) {
    __shared__ float As[BK][BM];    // transposed: As[k][m]
    __shared__ float Bs[BK][128];

    const int t = threadIdx.x;
    const int row0 = blockIdx.x * BM;
    const int tx = t & 15;
    const int ty = t >> 4;
    const int m0 = ty * 8;
    const int n0 = tx * 8;

    float acc[8][8];
    #pragma unroll
    for (int i = 0; i < 8; ++i)
        #pragma unroll
        for (int j = 0; j < 8; ++j) acc[i][j] = 0.f;

    for (int k0 = 0; k0 < 128; k0 += BK) {
        #pragma unroll
        for (int p = 0; p < 4; ++p) {
            int f = t + p * 256;          // 0..1023 float4 id
            int r = f >> 3;               // row in tile 0..127
            int cv = f & 7;               // float4 col 0..7
            int gr = row0 + r;
            float4 v = make_float4(0.f, 0.f, 0.f, 0.f);
            if (gr < M) v = *(const float4*)(&A[(size_t)gr * 128 + k0 + cv * 4]);
            As[cv * 4 + 0][r] = v.x;
            As[cv * 4 + 1][r] = v.y;
            As[cv * 4 + 2][r] = v.z;
            As[cv * 4 + 3][r] = v.w;
        }
        #pragma unroll
        for (int p = 0; p < 4; ++p) {
            int f = t + p * 256;
            int r = f >> 5;               // 0..31
            int cv = f & 31;              // float4 col 0..31
            *(float4*)(&Bs[r][cv * 4]) = *(const float4*)(&B[(size_t)(k0 + r) * 128 + cv * 4]);
        }
        __syncthreads();

        #pragma unroll
        for (int k = 0; k < BK; ++k) {
            float a[8], b[8];
            *(float4*)&a[0] = *(const float4*)&As[k][m0];
            *(float4*)&a[4] = *(const float4*)&As[k][m0 + 4];
            *(float4*)&b[0] = *(const float4*)&Bs[k][n0];
            *(float4*)&b[4] = *(const float4*)&Bs[k][n0 + 4];
            #pragma unroll
            for (int i = 0; i < 8; ++i)
                #pragma unroll
                for (int j = 0; j < 8; ++j)
                    acc[i][j] = fmaf(a[i], b[j], acc[i][j]);
        }
        __syncthreads();
    }

    float bb[8];
    #pragma unroll
    for (int j = 0; j < 8; ++j) bb[j] = bias[n0 + j];

    #pragma unroll
    for (int i = 0; i < 8; ++i) {
        int gr = row0 + m0 + i;
        if (gr < M) {
            float rs = rowscale[gr];
            float o[8];
            #pragma unroll
            for (int j = 0; j < 8; ++j) o[j] = (acc[i][j] + bb[j]) * rs;
            *(float4*)(&out[(size_t)gr * 128 + n0]) = *(float4*)&o[0];
            *(float4*)(&out[(size_t)gr * 128 + n0 + 4]) = *(float4*)&o[4];
        }
    }
}

// Partitioned histogram: 16 groups. Groups 0..7 count edge keys in range
// sub*ne/8..(sub+1)*ne/8; groups 8..15 count node keys similarly. Group's
// sub-index == blockIdx.x & 7 -> pinned XCD (round-robin dispatch), so each
// cnt range stays in one XCD's L2 and atomic lines don't bounce cross-XCD.
__global__ __launch_bounds__(256)
void hist16(const int* __restrict__ edge_idx, const int* __restrict__ node_idx,
            int* __restrict__ cnt_e, int* __restrict__ cnt_v,
            int nnz, int ne, int nv) {
    const int g = blockIdx.x & 15;
    const bool isE = g < 8;
    const int sub = g & 7;
    const int* key = isE ? edge_idx : node_idx;
    int* cnt = isE ? cnt_e : cnt_v;
    const int nseg = isE ? ne : nv;
    const int lo = (int)((long long)nseg * sub / 8);
    const int hi = (int)((long long)nseg * (sub + 1) / 8);
    const int nb = gridDim.x >> 4;
    const int bid = blockIdx.x >> 4;
    const int stride = nb * 256;
    for (int i = bid * 256 + threadIdx.x; i < nnz; i += stride) {
        int k = key[i];
        if (k >= lo && k < hi) atomicAdd(&cnt[k], 1);
    }
}

// Disjoint-range allocation: wave-level exclusive scan of counts, one global
// fetch-add per wave. Bucket ORDER in src arrays is arbitrary (only start+len
// matter), so no grid-wide prefix scan is needed.
// REQUIRES: ne % 64 == 0 and (ne+nv) % 64 == 0 so isE/oob are wave-uniform.
__global__ __launch_bounds__(256)
void alloc_ranges(const int* __restrict__ cnt_e, const int* __restrict__ cnt_v,
                  int* __restrict__ start_e, int* __restrict__ cursor_e,
                  int* __restrict__ start_v, int* __restrict__ cursor_v,
                  int* __restrict__ ctr, int ne, int nv) {
    int gid = blockIdx.x * 256 + threadIdx.x;
    int lane = threadIdx.x & 63;
    int total = ne + nv;
    if (gid - lane >= total) return;            // whole wave out of range
    bool isE = gid < ne;                        // wave-uniform (ne % 64 == 0)
    int idx = isE ? gid : gid - ne;
    int c = (gid < total) ? (isE ? cnt_e[idx] : cnt_v[idx]) : 0;
    int x = c;                                  // inclusive wave scan
    #pragma unroll
    for (int d = 1; d < 64; d <<= 1) {
        int y = __shfl_up(x, d);
        if (lane >= d) x += y;
    }
    int base;
    if (lane == 63) base = atomicAdd(isE ? &ctr[0] : &ctr[1], x);
    base = __shfl(base, 63);
    int pos = base + (x - c);
    if (gid < total) {
        if (isE) { start_e[idx] = pos; cursor_e[idx] = pos; }
        else     { start_v[idx] = pos; cursor_v[idx] = pos; }
    }
}

// Partitioned scatter, same 16-group scheme as hist16. Each group's cursor
// window (~20-100 KB) and src output window (~500 KB) are L2-resident on its
// XCD -> random 4B writes coalesce into once-evicted lines instead of 16x
// line-amplified HBM churn.
__global__ __launch_bounds__(256)
void scatter16(const int* __restrict__ edge_idx, const int* __restrict__ node_idx,
               int* __restrict__ cursor_e, int* __restrict__ cursor_v,
               int* __restrict__ src_e, int* __restrict__ src_v,
               int nnz, int ne, int nv) {
    const int g = blockIdx.x & 15;
    const bool isE = g < 8;
    const int sub = g & 7;
    const int* key = isE ? edge_idx : node_idx;
    const int* pay = isE ? node_idx : edge_idx;
    int* cursor = isE ? cursor_e : cursor_v;
    int* out = isE ? src_e : src_v;
    const int nseg = isE ? ne : nv;
    const int lo = (int)((long long)nseg * sub / 8);
    const int hi = (int)((long long)nseg * (sub + 1) / 8);
    const int nb = gridDim.x >> 4;
    const int bid = blockIdx.x >> 4;
    const int stride = nb * 256;
    for (int i = bid * 256 + threadIdx.x; i < nnz; i += stride) {
        int k = key[i];
        if (k >= lo && k < hi) {
            int p = atomicAdd(&cursor[k], 1);
            out[p] = pay[i];
        }
    }
}

// dst[seg][:] = (1/sum_tbl[seg]) * sum_{j} src[srcidx[start[seg]+j]][:]
// 32 lanes per segment (float4/lane), 4 independent accumulators for MLP.
__global__ __launch_bounds__(256)
void gather_rows(const float* __restrict__ src, const int* __restrict__ srcidx,
                 const int* __restrict__ start, const int* __restrict__ cnt,
                 const float* __restrict__ sum_tbl, float* __restrict__ dst, int nseg) {
    const int lane = threadIdx.x & 31;
    int seg = (blockIdx.x * 256 + threadIdx.x) >> 5;
    if (seg >= nseg) return;
    const int st = start[seg];
    const int len = cnt[seg];
    const int c4 = lane * 4;
    float4 a0 = make_float4(0, 0, 0, 0), a1 = a0, a2 = a0, a3 = a0;
    int j = 0;
    for (; j + 4 <= len; j += 4) {
        int n0 = srcidx[st + j + 0];
        int n1 = srcidx[st + j + 1];
        int n2 = srcidx[st + j + 2];
        int n3 = srcidx[st + j + 3];
        a0 = f4add(a0, *(const float4*)(&src[(size_t)n0 * 128 + c4]));
        a1 = f4add(a1, *(const float4*)(&src[(size_t)n1 * 128 + c4]));
        a2 = f4add(a2, *(const float4*)(&src[(size_t)n2 * 128 + c4]));
        a3 = f4add(a3, *(const float4*)(&src[(size_t)n3 * 128 + c4]));
    }
    for (; j < len; ++j) {
        int n = srcidx[st + j];
        a0 = f4add(a0, *(const float4*)(&src[(size_t)n * 128 + c4]));
    }
    float sc = 1.0f / sum_tbl[seg];
    float4 r = f4add(f4add(a0, a1), f4add(a2, a3));
    r.x *= sc; r.y *= sc; r.z *= sc; r.w *= sc;
    *(float4*)(&dst[(size_t)seg * 128 + c4]) = r;
}

extern "C" void kernel_launch(void* const* d_in, const int* in_sizes, int n_in,
                              void* d_out, int out_size, void* d_ws, size_t ws_size,
                              hipStream_t stream) {
    const float* vfeat        = (const float*)d_in[0];
    const float* v_reg_weight = (const float*)d_in[2];
    const float* v_reg_sum    = (const float*)d_in[3];
    const float* e_reg_weight = (const float*)d_in[4];
    const float* e_reg_sum    = (const float*)d_in[5];
    const int*   node_idx     = (const int*)d_in[6];
    const int*   edge_idx     = (const int*)d_in[7];
    const float* W1           = (const float*)d_in[8];
    const float* b1           = (const float*)d_in[9];
    const float* Wve          = (const float*)d_in[10];
    const float* bve          = (const float*)d_in[11];
    const float* Wev          = (const float*)d_in[12];
    const float* bev          = (const float*)d_in[13];

    const int N_V = in_sizes[2];   // 200000
    const int N_E = in_sizes[4];   // 40000
    const int NNZ = in_sizes[6];   // 1000000

    // ---- ws layout (bytes) ----
    char* w = (char*)d_ws;
    float* Wf       = (float*)(w + 0);          //    65,536
    float* bf       = (float*)(w + 65536);      //       512
    float* Whe      = (float*)(w + 66048);      // 20,480,000  [N_E,128]
    int*   cnt_e    = (int*)(w + 20546048);     //   160,000
    int*   cnt_v    = (int*)(w + 20706048);     //   800,000
    int*   ctr      = (int*)(w + 21506048);     //         8
    // zero region: cnt_e..ctr = 960,008 B starting at 20546048
    int*   start_e  = (int*)(w + 21506056);     //   160,000
    int*   cursor_e = (int*)(w + 21666056);     //   160,000
    int*   start_v  = (int*)(w + 21826056);     //   800,000
    int*   cursor_v = (int*)(w + 22626056);     //   800,000
    int*   src_e    = (int*)(w + 23426056);     // 4,000,000
    int*   src_v    = (int*)(w + 27426056);     // 4,000,000  (end 31,426,056)

    float* feat_v_out = (float*)d_out;                       // [N_V,128]
    float* feat_e     = (float*)d_out + (size_t)N_V * 128;   // [N_E,128]
    float* Whv        = feat_v_out;  // chunk1 doubles as scratch for Whv' (dead
                                     // before the final gather overwrites it)

    hipMemsetAsync(w + 20546048, 0, 960008, stream);

    fuse_weights<<<129, 128, 0, stream>>>(W1, b1, Wve, bve, Wf, bf);

    hist16<<<4096, 256, 0, stream>>>(edge_idx, node_idx, cnt_e, cnt_v, NNZ, N_E, N_V);

    alloc_ranges<<<(N_E + N_V + 255) / 256, 256, 0, stream>>>(
        cnt_e, cnt_v, start_e, cursor_e, start_v, cursor_v, ctr, N_E, N_V);

    gemm128<<<(N_V + BM - 1) / BM, 256, 0, stream>>>(vfeat, Wf, bf, v_reg_weight, Whv, N_V);

    scatter16<<<4096, 256, 0, stream>>>(edge_idx, node_idx,
                                        cursor_e, cursor_v, src_e, src_v, NNZ, N_E, N_V);

    gather_rows<<<(N_E * 32 + 255) / 256, 256, 0, stream>>>(
        Whv, src_e, start_e, cnt_e, e_reg_sum, feat_e, N_E);

    gemm128<<<(N_E + BM - 1) / BM, 256, 0, stream>>>(feat_e, Wev, bev, e_reg_weight, Whe, N_E);

    gather_rows<<<(N_V * 32 + 255) / 256, 256, 0, stream>>>(
        Whe, src_v, start_v, cnt_v, v_reg_sum, feat_v_out, N_V);
}